// Round 1
// baseline (499.997 us; speedup 1.0000x reference)
//
#include <hip/hip_runtime.h>
#include <math.h>

namespace {
constexpr int kB = 256;
constexpr int kD = 128;
constexpr int kN = 500000;
constexpr int kKC = 2049;             // K + 1
constexpr int kNPair = kB * kKC;      // 524544
constexpr float kTInv = 1.0f / 0.07f;
constexpr float kMom = 0.5f;
constexpr int kRB = 256;              // reduction grid size
}

// One wave (64 lanes) per (b, k) pair: loads memory_v1[idx] and memory_v2[idx]
// rows (512 B each, float2/lane), dots against teacher[b]/student[b] (L1/L2
// resident), 6-step shuffle reduce, lane 0 writes exp(dot/T).
__global__ __launch_bounds__(256) void dots_kernel(
    const float* __restrict__ mem1, const float* __restrict__ mem2,
    const float* __restrict__ teacher, const float* __restrict__ student,
    const int* __restrict__ cidx,
    float* __restrict__ e2, float* __restrict__ e1)
{
    int gtid = blockIdx.x * 256 + threadIdx.x;
    int wave = gtid >> 6;
    int lane = threadIdx.x & 63;
    if (wave >= kNPair) return;
    int b = wave / kKC;
    long long row = (long long)cidx[wave] * kD;
    const float2 m1 = *reinterpret_cast<const float2*>(mem1 + row + lane * 2);
    const float2 m2 = *reinterpret_cast<const float2*>(mem2 + row + lane * 2);
    const float2 tv = *reinterpret_cast<const float2*>(teacher + b * kD + lane * 2);
    const float2 sv = *reinterpret_cast<const float2*>(student + b * kD + lane * 2);
    float d1 = m1.x * tv.x + m1.y * tv.y;   // memory_v1 . teacher -> out_v2
    float d2 = m2.x * sv.x + m2.y * sv.y;   // memory_v2 . student -> out_v1
    #pragma unroll
    for (int off = 32; off > 0; off >>= 1) {
        d1 += __shfl_xor(d1, off);
        d2 += __shfl_xor(d2, off);
    }
    if (lane == 0) {
        e2[wave] = __expf(d1 * kTInv);
        e1[wave] = __expf(d2 * kTInv);
    }
}

// Deterministic block-partial sums of both exp arrays.
__global__ __launch_bounds__(256) void sums_kernel(
    const float* __restrict__ e2, const float* __restrict__ e1,
    float* __restrict__ p2, float* __restrict__ p1)
{
    __shared__ float s2[256], s1[256];
    float a2 = 0.f, a1 = 0.f;
    for (int i = blockIdx.x * 256 + threadIdx.x; i < kNPair; i += 256 * kRB) {
        a2 += e2[i];
        a1 += e1[i];
    }
    s2[threadIdx.x] = a2; s1[threadIdx.x] = a1;
    __syncthreads();
    for (int st = 128; st > 0; st >>= 1) {
        if ((int)threadIdx.x < st) {
            s2[threadIdx.x] += s2[threadIdx.x + st];
            s1[threadIdx.x] += s1[threadIdx.x + st];
        }
        __syncthreads();
    }
    if (threadIdx.x == 0) { p2[blockIdx.x] = s2[0]; p1[blockIdx.x] = s1[0]; }
}

// Reduce partials -> z (= mean * N).
__global__ __launch_bounds__(256) void z_kernel(
    const float* __restrict__ p2, const float* __restrict__ p1, float* __restrict__ z)
{
    __shared__ float s2[256], s1[256];
    s2[threadIdx.x] = p2[threadIdx.x];
    s1[threadIdx.x] = p1[threadIdx.x];
    __syncthreads();
    for (int st = 128; st > 0; st >>= 1) {
        if ((int)threadIdx.x < st) {
            s2[threadIdx.x] += s2[threadIdx.x + st];
            s1[threadIdx.x] += s1[threadIdx.x + st];
        }
        __syncthreads();
    }
    if (threadIdx.x == 0) {
        const float scale = (float)kN / (float)kNPair;
        z[0] = s2[0] * scale;   // z_v2
        z[1] = s1[0] * scale;   // z_v1
    }
}

// Elementwise log terms + block-partial loss sums.
__global__ __launch_bounds__(256) void lossp_kernel(
    const float* __restrict__ e2, const float* __restrict__ e1,
    const float* __restrict__ z, float* __restrict__ lp)
{
    const float mpn = 2048.0f / 500000.0f;
    const float noise = mpn + 1e-7f;
    const float iz2 = 1.0f / z[0];
    const float iz1 = 1.0f / z[1];
    float acc = 0.f;
    for (int i = blockIdx.x * 256 + threadIdx.x; i < kNPair; i += 256 * kRB) {
        int k = i % kKC;
        float x2 = e2[i] * iz2;
        float x1 = e1[i] * iz1;
        if (k == 0) {
            acc += __logf(x2 / (x2 + noise)) + __logf(x1 / (x1 + noise));
        } else {
            acc += __logf(mpn / (x2 + noise)) + __logf(mpn / (x1 + noise));
        }
    }
    __shared__ float s[256];
    s[threadIdx.x] = acc;
    __syncthreads();
    for (int st = 128; st > 0; st >>= 1) {
        if ((int)threadIdx.x < st) s[threadIdx.x] += s[threadIdx.x + st];
        __syncthreads();
    }
    if (threadIdx.x == 0) lp[blockIdx.x] = s[0];
}

__global__ __launch_bounds__(256) void final_kernel(
    const float* __restrict__ lp, float* __restrict__ out)
{
    __shared__ float s[256];
    s[threadIdx.x] = lp[threadIdx.x];
    __syncthreads();
    for (int st = 128; st > 0; st >>= 1) {
        if ((int)threadIdx.x < st) s[threadIdx.x] += s[threadIdx.x + st];
        __syncthreads();
    }
    if (threadIdx.x == 0) out[0] = -s[0] / (float)kB;
}

// One wave per b: momentum update + L2 normalize the pos_idx rows, written
// over the already-copied output banks. Last-wins on duplicate indices to
// match numpy scatter semantics. Scalar stores (d_out+1 breaks float2 align).
__global__ __launch_bounds__(64) void update_kernel(
    const float* __restrict__ mem1, const float* __restrict__ mem2,
    const float* __restrict__ student, const float* __restrict__ teacher,
    const int* __restrict__ pos_idx,
    float* __restrict__ out1, float* __restrict__ out2)
{
    int b = blockIdx.x;
    int lane = threadIdx.x;
    int p = pos_idx[b];
    for (int b2 = b + 1; b2 < kB; ++b2)
        if (pos_idx[b2] == p) return;   // a later write wins
    long long row = (long long)p * kD;
    float2 m1 = *reinterpret_cast<const float2*>(mem1 + row + lane * 2);
    float2 m2 = *reinterpret_cast<const float2*>(mem2 + row + lane * 2);
    float2 sv = *reinterpret_cast<const float2*>(student + b * kD + lane * 2);
    float2 tv = *reinterpret_cast<const float2*>(teacher + b * kD + lane * 2);
    // v1 pairs with student, v2 pairs with teacher (per reference)
    float2 l1 = make_float2(m1.x * kMom + sv.x * (1.f - kMom),
                            m1.y * kMom + sv.y * (1.f - kMom));
    float2 l2 = make_float2(m2.x * kMom + tv.x * (1.f - kMom),
                            m2.y * kMom + tv.y * (1.f - kMom));
    float n1 = l1.x * l1.x + l1.y * l1.y;
    float n2 = l2.x * l2.x + l2.y * l2.y;
    #pragma unroll
    for (int off = 32; off > 0; off >>= 1) {
        n1 += __shfl_xor(n1, off);
        n2 += __shfl_xor(n2, off);
    }
    float i1 = 1.0f / sqrtf(n1);
    float i2 = 1.0f / sqrtf(n2);
    out1[row + lane * 2]     = l1.x * i1;
    out1[row + lane * 2 + 1] = l1.y * i1;
    out2[row + lane * 2]     = l2.x * i2;
    out2[row + lane * 2 + 1] = l2.y * i2;
}

extern "C" void kernel_launch(void* const* d_in, const int* in_sizes, int n_in,
                              void* d_out, int out_size, void* d_ws, size_t ws_size,
                              hipStream_t stream) {
    const float* student = (const float*)d_in[0];
    const float* teacher = (const float*)d_in[1];
    const float* mem1    = (const float*)d_in[2];
    const float* mem2    = (const float*)d_in[3];
    const int*   pos_idx = (const int*)d_in[4];
    const int*   cidx    = (const int*)d_in[5];

    float* out  = (float*)d_out;
    float* out1 = out + 1;                            // new_memory_v1
    float* out2 = out + 1 + (long long)kN * kD;       // new_memory_v2

    float* ws = (float*)d_ws;
    float* e2 = ws;                   // exps for out_v2 (mem1 . teacher)
    float* e1 = ws + kNPair;          // exps for out_v1 (mem2 . student)
    float* p2 = e1 + kNPair;
    float* p1 = p2 + kRB;
    float* zz = p1 + kRB;
    float* lp = zz + 2;

    // ---- loss path ----
    int nblocks = (kNPair + 3) / 4;   // 4 waves per 256-thread block
    dots_kernel<<<nblocks, 256, 0, stream>>>(mem1, mem2, teacher, student, cidx, e2, e1);
    sums_kernel<<<kRB, 256, 0, stream>>>(e2, e1, p2, p1);
    z_kernel<<<1, 256, 0, stream>>>(p2, p1, zz);
    lossp_kernel<<<kRB, 256, 0, stream>>>(e2, e1, zz, lp);
    final_kernel<<<1, 256, 0, stream>>>(lp, out);

    // ---- memory bank update: bulk copy, then scatter the 256 updated rows ----
    size_t bytes = (size_t)kN * kD * sizeof(float);
    hipMemcpyAsync(out1, mem1, bytes, hipMemcpyDeviceToDevice, stream);
    hipMemcpyAsync(out2, mem2, bytes, hipMemcpyDeviceToDevice, stream);
    update_kernel<<<kB, 64, 0, stream>>>(mem1, mem2, student, teacher, pos_idx, out1, out2);
}

// Round 2
// 372.732 us; speedup vs baseline: 1.3414x; 1.3414x over previous
//
#include <hip/hip_runtime.h>
#include <math.h>

namespace {
constexpr int kB = 256;
constexpr int kD = 128;
constexpr int kN = 500000;
constexpr int kKC = 2049;             // K + 1
constexpr int kNPair = kB * kKC;      // 524544
constexpr float kTInv = 1.0f / 0.07f;
constexpr float kMom = 0.5f;
constexpr int kRB = 256;              // reduction grid size
constexpr long long kM = (long long)kN * kD;    // 64,000,000 floats per bank
constexpr long long kTot = 2 * kM;              // 128,000,000
}

// One wave (64 lanes) per (b, k) pair: loads memory_v1[idx] and memory_v2[idx]
// rows (512 B each, float2/lane), dots against teacher[b]/student[b] (cache
// resident), 6-step shuffle reduce, lane 0 writes exp(dot/T).
__global__ __launch_bounds__(256) void dots_kernel(
    const float* __restrict__ mem1, const float* __restrict__ mem2,
    const float* __restrict__ teacher, const float* __restrict__ student,
    const int* __restrict__ cidx,
    float* __restrict__ e2, float* __restrict__ e1)
{
    int gtid = blockIdx.x * 256 + threadIdx.x;
    int wave = gtid >> 6;
    int lane = threadIdx.x & 63;
    if (wave >= kNPair) return;
    int b = wave / kKC;
    long long row = (long long)cidx[wave] * kD;
    const float2 m1 = *reinterpret_cast<const float2*>(mem1 + row + lane * 2);
    const float2 m2 = *reinterpret_cast<const float2*>(mem2 + row + lane * 2);
    const float2 tv = *reinterpret_cast<const float2*>(teacher + b * kD + lane * 2);
    const float2 sv = *reinterpret_cast<const float2*>(student + b * kD + lane * 2);
    float d1 = m1.x * tv.x + m1.y * tv.y;   // memory_v1 . teacher -> out_v2
    float d2 = m2.x * sv.x + m2.y * sv.y;   // memory_v2 . student -> out_v1
    #pragma unroll
    for (int off = 32; off > 0; off >>= 1) {
        d1 += __shfl_xor(d1, off);
        d2 += __shfl_xor(d2, off);
    }
    if (lane == 0) {
        e2[wave] = __expf(d1 * kTInv);
        e1[wave] = __expf(d2 * kTInv);
    }
}

// Deterministic block-partial sums of both exp arrays.
__global__ __launch_bounds__(256) void sums_kernel(
    const float* __restrict__ e2, const float* __restrict__ e1,
    float* __restrict__ p2, float* __restrict__ p1)
{
    __shared__ float s2[256], s1[256];
    float a2 = 0.f, a1 = 0.f;
    for (int i = blockIdx.x * 256 + threadIdx.x; i < kNPair; i += 256 * kRB) {
        a2 += e2[i];
        a1 += e1[i];
    }
    s2[threadIdx.x] = a2; s1[threadIdx.x] = a1;
    __syncthreads();
    for (int st = 128; st > 0; st >>= 1) {
        if ((int)threadIdx.x < st) {
            s2[threadIdx.x] += s2[threadIdx.x + st];
            s1[threadIdx.x] += s1[threadIdx.x + st];
        }
        __syncthreads();
    }
    if (threadIdx.x == 0) { p2[blockIdx.x] = s2[0]; p1[blockIdx.x] = s1[0]; }
}

// Reduce partials -> z (= mean * N).
__global__ __launch_bounds__(256) void z_kernel(
    const float* __restrict__ p2, const float* __restrict__ p1, float* __restrict__ z)
{
    __shared__ float s2[256], s1[256];
    s2[threadIdx.x] = p2[threadIdx.x];
    s1[threadIdx.x] = p1[threadIdx.x];
    __syncthreads();
    for (int st = 128; st > 0; st >>= 1) {
        if ((int)threadIdx.x < st) {
            s2[threadIdx.x] += s2[threadIdx.x + st];
            s1[threadIdx.x] += s1[threadIdx.x + st];
        }
        __syncthreads();
    }
    if (threadIdx.x == 0) {
        const float scale = (float)kN / (float)kNPair;
        z[0] = s2[0] * scale;   // z_v2
        z[1] = s1[0] * scale;   // z_v1
    }
}

// Elementwise log terms + block-partial loss sums.
__global__ __launch_bounds__(256) void lossp_kernel(
    const float* __restrict__ e2, const float* __restrict__ e1,
    const float* __restrict__ z, float* __restrict__ lp)
{
    const float mpn = 2048.0f / 500000.0f;
    const float noise = mpn + 1e-7f;
    const float iz2 = 1.0f / z[0];
    const float iz1 = 1.0f / z[1];
    float acc = 0.f;
    for (int i = blockIdx.x * 256 + threadIdx.x; i < kNPair; i += 256 * kRB) {
        int k = i % kKC;
        float x2 = e2[i] * iz2;
        float x1 = e1[i] * iz1;
        if (k == 0) {
            acc += __logf(x2 / (x2 + noise)) + __logf(x1 / (x1 + noise));
        } else {
            acc += __logf(mpn / (x2 + noise)) + __logf(mpn / (x1 + noise));
        }
    }
    __shared__ float s[256];
    s[threadIdx.x] = acc;
    __syncthreads();
    for (int st = 128; st > 0; st >>= 1) {
        if ((int)threadIdx.x < st) s[threadIdx.x] += s[threadIdx.x + st];
        __syncthreads();
    }
    if (threadIdx.x == 0) lp[blockIdx.x] = s[0];
}

__global__ __launch_bounds__(256) void final_kernel(
    const float* __restrict__ lp, float* __restrict__ out)
{
    __shared__ float s[256];
    s[threadIdx.x] = lp[threadIdx.x];
    __syncthreads();
    for (int st = 128; st > 0; st >>= 1) {
        if ((int)threadIdx.x < st) s[threadIdx.x] += s[threadIdx.x + st];
        __syncthreads();
    }
    if (threadIdx.x == 0) out[0] = -s[0] / (float)kB;
}

// Fused bulk copy of both banks into out[1..kTot] with ALIGNED float4 stores.
// out4[k] (k>=1) covers out[4k..4k+3] = srcconcat[4k-1..4k+2]; rebuilt from
// two adjacent aligned float4 loads (duplicate line reads hit L2). Only
// k == kM/4 straddles the bank boundary; k == 0 writes out[1..3] + tail
// scalar, never touching the loss scalar at out[0].
__global__ __launch_bounds__(256) void copy_kernel(
    const float* __restrict__ mem1, const float* __restrict__ mem2,
    float* __restrict__ out)
{
    const long long NV4 = (kTot + 1) / 4;     // 32,000,000 float4 stores
    const long long KS  = kM / 4;             // 16,000,000: boundary index
    const float4* m1v = reinterpret_cast<const float4*>(mem1);
    const float4* m2v = reinterpret_cast<const float4*>(mem2);
    float4* ov = reinterpret_cast<float4*>(out);
    long long stride = (long long)gridDim.x * 256;
    for (long long k = (long long)blockIdx.x * 256 + threadIdx.x; k < NV4; k += stride) {
        if (k == 0) {
            out[1] = mem1[0]; out[2] = mem1[1]; out[3] = mem1[2];
            out[kTot] = mem2[kM - 1];         // final tail element
            continue;
        }
        float4 r;
        if (k < KS) {
            float4 a = m1v[k - 1];
            float4 b = m1v[k];
            r = make_float4(a.w, b.x, b.y, b.z);
        } else if (k == KS) {
            r = make_float4(mem1[kM - 1], mem2[0], mem2[1], mem2[2]);
        } else {
            float4 a = m2v[k - KS - 1];
            float4 b = m2v[k - KS];
            r = make_float4(a.w, b.x, b.y, b.z);
        }
        ov[k] = r;
    }
}

// One wave per b: momentum update + L2 normalize the pos_idx rows, written
// over the already-copied output banks. Last-wins on duplicate indices to
// match numpy scatter semantics. Scalar stores (d_out+1 breaks alignment).
__global__ __launch_bounds__(64) void update_kernel(
    const float* __restrict__ mem1, const float* __restrict__ mem2,
    const float* __restrict__ student, const float* __restrict__ teacher,
    const int* __restrict__ pos_idx,
    float* __restrict__ out1, float* __restrict__ out2)
{
    int b = blockIdx.x;
    int lane = threadIdx.x;
    int p = pos_idx[b];
    for (int b2 = b + 1; b2 < kB; ++b2)
        if (pos_idx[b2] == p) return;   // a later write wins
    long long row = (long long)p * kD;
    float2 m1 = *reinterpret_cast<const float2*>(mem1 + row + lane * 2);
    float2 m2 = *reinterpret_cast<const float2*>(mem2 + row + lane * 2);
    float2 sv = *reinterpret_cast<const float2*>(student + b * kD + lane * 2);
    float2 tv = *reinterpret_cast<const float2*>(teacher + b * kD + lane * 2);
    // v1 pairs with student, v2 pairs with teacher (per reference)
    float2 l1 = make_float2(m1.x * kMom + sv.x * (1.f - kMom),
                            m1.y * kMom + sv.y * (1.f - kMom));
    float2 l2 = make_float2(m2.x * kMom + tv.x * (1.f - kMom),
                            m2.y * kMom + tv.y * (1.f - kMom));
    float n1 = l1.x * l1.x + l1.y * l1.y;
    float n2 = l2.x * l2.x + l2.y * l2.y;
    #pragma unroll
    for (int off = 32; off > 0; off >>= 1) {
        n1 += __shfl_xor(n1, off);
        n2 += __shfl_xor(n2, off);
    }
    float i1 = 1.0f / sqrtf(n1);
    float i2 = 1.0f / sqrtf(n2);
    out1[row + lane * 2]     = l1.x * i1;
    out1[row + lane * 2 + 1] = l1.y * i1;
    out2[row + lane * 2]     = l2.x * i2;
    out2[row + lane * 2 + 1] = l2.y * i2;
}

extern "C" void kernel_launch(void* const* d_in, const int* in_sizes, int n_in,
                              void* d_out, int out_size, void* d_ws, size_t ws_size,
                              hipStream_t stream) {
    const float* student = (const float*)d_in[0];
    const float* teacher = (const float*)d_in[1];
    const float* mem1    = (const float*)d_in[2];
    const float* mem2    = (const float*)d_in[3];
    const int*   pos_idx = (const int*)d_in[4];
    const int*   cidx    = (const int*)d_in[5];

    float* out  = (float*)d_out;
    float* out1 = out + 1;                // new_memory_v1
    float* out2 = out + 1 + kM;           // new_memory_v2

    float* ws = (float*)d_ws;
    float* e2 = ws;                   // exps for out_v2 (mem1 . teacher)
    float* e1 = ws + kNPair;          // exps for out_v1 (mem2 . student)
    float* p2 = e1 + kNPair;
    float* p1 = p2 + kRB;
    float* zz = p1 + kRB;
    float* lp = zz + 2;

    // ---- loss path ----
    int nblocks = (kNPair + 3) / 4;   // 4 waves per 256-thread block
    dots_kernel<<<nblocks, 256, 0, stream>>>(mem1, mem2, teacher, student, cidx, e2, e1);
    sums_kernel<<<kRB, 256, 0, stream>>>(e2, e1, p2, p1);
    z_kernel<<<1, 256, 0, stream>>>(p2, p1, zz);
    lossp_kernel<<<kRB, 256, 0, stream>>>(e2, e1, zz, lp);
    final_kernel<<<1, 256, 0, stream>>>(lp, out);

    // ---- memory bank update: fused aligned copy, then scatter 256 rows ----
    copy_kernel<<<2048, 256, 0, stream>>>(mem1, mem2, out);
    update_kernel<<<kB, 64, 0, stream>>>(mem1, mem2, student, teacher, pos_idx, out1, out2);
}